// Round 13
// baseline (4814.557 us; speedup 1.0000x reference)
//
#include <hip/hip_runtime.h>

// ---------------------------------------------------------------------------
// SNN two-layer SNU — bit-exact to the np referee (identified rounds 0-9):
//   * matmul: per element, fp32 ascending-k FMA chain, single flush (plain
//     f32 add) at k=512   -> two half-K passes, pass2 does C += chain
//   * recurrence: fp32, numpy op order, NO fma contraction
// Round 13: software-pipelined GEMM (prefetch next tile during compute,
// double-buffered LDS, one barrier/iter) + float4-vectorized scans.
// ---------------------------------------------------------------------------

#define BM 256
#define BN 128
#define BKK 16
#define LDA (BM + 4)
#define LDB (BN + 4)
#define NT  (512 / BKK)

template<int ADD>
__global__ __launch_bounds__(256) void gemm_nt_half(
    const float* __restrict__ A,
    const float* __restrict__ B,
    float* __restrict__ C,
    int N, int M, int K, int kbase)
{
#pragma clang fp contract(off)
    __shared__ float As[2][BKK][LDA];
    __shared__ float Bs[2][BKK][LDB];

    const int tid  = threadIdx.x;
    const int wave = tid >> 6;
    const int lane = tid & 63;
    const int tx   = lane & 7;
    const int ty   = lane >> 3;
    const int wr   = wave >> 1;
    const int wc   = wave & 1;
    const int row0 = wr * 128 + ty * 8;
    const int col0 = wc * 64 + tx * 8;

    const int n0 = blockIdx.x * BM;
    const int m0 = blockIdx.y * BN;

    const int ar = tid >> 1;            // 0..127
    const int ka = (tid & 1) * 8;       // 0 or 8

    const float* Ap0 = A + (size_t)(n0 + ar) * K + kbase + ka;
    const float* Ap1 = A + (size_t)(n0 + 128 + ar) * K + kbase + ka;
    const float* Bp  = B + (size_t)(m0 + ar) * K + kbase + ka;

    float4 ra00, ra01, ra10, ra11, rb0, rb1;

    auto LOAD = [&](int kt) {
        const int k0 = kt * BKK;
        ra00 = *(const float4*)(Ap0 + k0);
        ra01 = *(const float4*)(Ap0 + k0 + 4);
        ra10 = *(const float4*)(Ap1 + k0);
        ra11 = *(const float4*)(Ap1 + k0 + 4);
        rb0  = *(const float4*)(Bp + k0);
        rb1  = *(const float4*)(Bp + k0 + 4);
    };
    auto STORE = [&](int buf) {
        As[buf][ka+0][ar]     = ra00.x; As[buf][ka+1][ar]     = ra00.y;
        As[buf][ka+2][ar]     = ra00.z; As[buf][ka+3][ar]     = ra00.w;
        As[buf][ka+4][ar]     = ra01.x; As[buf][ka+5][ar]     = ra01.y;
        As[buf][ka+6][ar]     = ra01.z; As[buf][ka+7][ar]     = ra01.w;
        As[buf][ka+0][128+ar] = ra10.x; As[buf][ka+1][128+ar] = ra10.y;
        As[buf][ka+2][128+ar] = ra10.z; As[buf][ka+3][128+ar] = ra10.w;
        As[buf][ka+4][128+ar] = ra11.x; As[buf][ka+5][128+ar] = ra11.y;
        As[buf][ka+6][128+ar] = ra11.z; As[buf][ka+7][128+ar] = ra11.w;
        Bs[buf][ka+0][ar]     = rb0.x;  Bs[buf][ka+1][ar]     = rb0.y;
        Bs[buf][ka+2][ar]     = rb0.z;  Bs[buf][ka+3][ar]     = rb0.w;
        Bs[buf][ka+4][ar]     = rb1.x;  Bs[buf][ka+5][ar]     = rb1.y;
        Bs[buf][ka+6][ar]     = rb1.z;  Bs[buf][ka+7][ar]     = rb1.w;
    };

    float acc[2][8][8];
#pragma unroll
    for (int c = 0; c < 2; ++c)
#pragma unroll
        for (int i = 0; i < 8; ++i)
#pragma unroll
            for (int j = 0; j < 8; ++j) acc[c][i][j] = 0.f;

    LOAD(0);
    STORE(0);
    __syncthreads();

    for (int kt = 0; kt < NT; ++kt) {
        const int cur = kt & 1;
        if (kt + 1 < NT) LOAD(kt + 1);   // issue early: latency hides under FMAs
#pragma unroll
        for (int k = 0; k < BKK; ++k) {
            float4 a0f = *(const float4*)&As[cur][k][row0];
            float4 a1f = *(const float4*)&As[cur][k][row0 + 4];
            float4 a2f = *(const float4*)&As[cur][k][row0 + 64];
            float4 a3f = *(const float4*)&As[cur][k][row0 + 68];
            float4 b0f = *(const float4*)&Bs[cur][k][col0];
            float4 b1f = *(const float4*)&Bs[cur][k][col0 + 4];
            float av0[8] = {a0f.x,a0f.y,a0f.z,a0f.w, a1f.x,a1f.y,a1f.z,a1f.w};
            float av1[8] = {a2f.x,a2f.y,a2f.z,a2f.w, a3f.x,a3f.y,a3f.z,a3f.w};
            float bv [8] = {b0f.x,b0f.y,b0f.z,b0f.w, b1f.x,b1f.y,b1f.z,b1f.w};
#pragma unroll
            for (int i = 0; i < 8; ++i)
#pragma unroll
                for (int j = 0; j < 8; ++j) {
                    acc[0][i][j] = __builtin_fmaf(av0[i], bv[j], acc[0][i][j]);
                    acc[1][i][j] = __builtin_fmaf(av1[i], bv[j], acc[1][i][j]);
                }
        }
        if (kt + 1 < NT) {
            STORE((kt + 1) & 1);         // write other buffer; readers of it
            __syncthreads();             // finished at the previous barrier
        }
    }

#pragma unroll
    for (int c = 0; c < 2; ++c) {
#pragma unroll
        for (int i = 0; i < 8; ++i) {
            size_t row = (size_t)(n0 + wr * 128 + c * 64 + ty * 8 + i);
            float* Cp = C + row * M + m0 + col0;
            if (ADD) {
                float4 o0 = *(float4*)Cp;
                float4 o1 = *(float4*)(Cp + 4);
                o0.x = o0.x + acc[c][i][0]; o0.y = o0.y + acc[c][i][1];
                o0.z = o0.z + acc[c][i][2]; o0.w = o0.w + acc[c][i][3];
                o1.x = o1.x + acc[c][i][4]; o1.y = o1.y + acc[c][i][5];
                o1.z = o1.z + acc[c][i][6]; o1.w = o1.w + acc[c][i][7];
                *(float4*)Cp       = o0;
                *(float4*)(Cp + 4) = o1;
            } else {
                float4 o0 = {acc[c][i][0], acc[c][i][1], acc[c][i][2], acc[c][i][3]};
                float4 o1 = {acc[c][i][4], acc[c][i][5], acc[c][i][6], acc[c][i][7]};
                *(float4*)Cp       = o0;
                *(float4*)(Cp + 4) = o1;
            }
        }
    }
}

// Layer-1 recurrence, float4-vectorized, numpy op order, contraction off.
__global__ __launch_bounds__(256) void scan_l1v(
    const float* __restrict__ Z, const float* __restrict__ bias,
    float* __restrict__ spikes, float* __restrict__ mem, int T, int BH)
{
#pragma clang fp contract(off)
    const int BH4 = BH >> 2;
    int i4 = blockIdx.x * blockDim.x + threadIdx.x;
    if (i4 >= BH4) return;
    const float4* Zv = (const float4*)Z;
    float4* spv  = (float4*)spikes;
    float4* memv = (float4*)mem;
    const float4 bb = *(const float4*)&bias[(i4 << 2) & 1023];

    float4 s = {0.f,0.f,0.f,0.f}, y = {0.f,0.f,0.f,0.f};
    float4 z = Zv[i4];
    for (int t = 0; t < T; ++t) {
        size_t idx = (size_t)t * BH4 + i4;
        float4 zn;
        if (t + 1 < T) zn = Zv[idx + BH4]; else zn = make_float4(0.f,0.f,0.f,0.f);
        float u;
        u = z.x + (0.8f * s.x) * (1.0f - y.x); s.x = fmaxf(u, 0.f); y.x = ((s.x + bb.x) > 0.f) ? 1.f : 0.f;
        u = z.y + (0.8f * s.y) * (1.0f - y.y); s.y = fmaxf(u, 0.f); y.y = ((s.y + bb.y) > 0.f) ? 1.f : 0.f;
        u = z.z + (0.8f * s.z) * (1.0f - y.z); s.z = fmaxf(u, 0.f); y.z = ((s.z + bb.z) > 0.f) ? 1.f : 0.f;
        u = z.w + (0.8f * s.w) * (1.0f - y.w); s.w = fmaxf(u, 0.f); y.w = ((s.w + bb.w) > 0.f) ? 1.f : 0.f;
        spv[idx]  = y;
        memv[idx] = s;
        z = zn;
    }
}

// Layer-2 recurrence, float4-vectorized, in place Z2 -> mem2.
__global__ __launch_bounds__(256) void scan_l2v(
    float* __restrict__ Z, const float* __restrict__ bias, int T, int BH)
{
#pragma clang fp contract(off)
    const int BH4 = BH >> 2;
    int i4 = blockIdx.x * blockDim.x + threadIdx.x;
    if (i4 >= BH4) return;
    float4* Zv = (float4*)Z;
    const float4 bb = *(const float4*)&bias[(i4 << 2) & 1023];

    float4 s = {0.f,0.f,0.f,0.f}, y = {0.f,0.f,0.f,0.f};
    float4 z = Zv[i4];
    for (int t = 0; t < T; ++t) {
        size_t idx = (size_t)t * BH4 + i4;
        float4 zn;
        if (t + 1 < T) zn = Zv[idx + BH4]; else zn = make_float4(0.f,0.f,0.f,0.f);
        float u;
        u = z.x + (0.8f * s.x) * (1.0f - y.x); s.x = fmaxf(u, 0.f); y.x = ((s.x + bb.x) > 0.f) ? 1.f : 0.f;
        u = z.y + (0.8f * s.y) * (1.0f - y.y); s.y = fmaxf(u, 0.f); y.y = ((s.y + bb.y) > 0.f) ? 1.f : 0.f;
        u = z.z + (0.8f * s.z) * (1.0f - y.z); s.z = fmaxf(u, 0.f); y.z = ((s.z + bb.z) > 0.f) ? 1.f : 0.f;
        u = z.w + (0.8f * s.w) * (1.0f - y.w); s.w = fmaxf(u, 0.f); y.w = ((s.w + bb.w) > 0.f) ? 1.f : 0.f;
        Zv[idx] = s;
        z = zn;
    }
}

extern "C" void kernel_launch(void* const* d_in, const int* in_sizes, int n_in,
                              void* d_out, int out_size, void* d_ws, size_t ws_size,
                              hipStream_t stream)
{
    (void)in_sizes; (void)n_in; (void)out_size; (void)d_ws; (void)ws_size;

    const float* x  = (const float*)d_in[0];   // [T,B,IN]
    const float* W1 = (const float*)d_in[1];   // [H,IN]
    const float* b1 = (const float*)d_in[2];   // [H]
    const float* W2 = (const float*)d_in[3];   // [H,H]
    const float* b2 = (const float*)d_in[4];   // [H]
    float* out = (float*)d_out;

    const int T = 100, Bsz = 256, IN = 1024, H = 1024;
    const int N  = T * Bsz;                 // 25600
    const int BH = Bsz * H;                 // 262144
    const size_t TBH = (size_t)T * BH;      // 26214400

    float* spikes = out;                    // output 0
    float* mem1   = out + TBH;              // output 1
    float* zbuf   = out + 2 * TBH;          // Z1 -> Z2 -> mem2 (in place)

    dim3 ggrid(N / BM, H / BN);             // 100 x 8
    dim3 gblk(256);
    dim3 sgrid((BH / 4) / 256);             // 256 blocks
    dim3 sblk(256);

    // Z1 = X @ W1^T  (two k-half passes)
    gemm_nt_half<0><<<ggrid, gblk, 0, stream>>>(x, W1, zbuf, N, H, IN, 0);
    gemm_nt_half<1><<<ggrid, gblk, 0, stream>>>(x, W1, zbuf, N, H, IN, 512);
    // layer-1 scan -> spikes, mem1
    scan_l1v<<<sgrid, sblk, 0, stream>>>(zbuf, b1, spikes, mem1, T, BH);
    // Z2 = spikes @ W2^T
    gemm_nt_half<0><<<ggrid, gblk, 0, stream>>>(spikes, W2, zbuf, N, H, H, 0);
    gemm_nt_half<1><<<ggrid, gblk, 0, stream>>>(spikes, W2, zbuf, N, H, H, 512);
    // layer-2 scan in place -> mem2
    scan_l2v<<<sgrid, sblk, 0, stream>>>(zbuf, b2, T, BH);
}

// Round 14
// 1489.363 us; speedup vs baseline: 3.2326x; 3.2326x over previous
//
#include <hip/hip_runtime.h>

// ---------------------------------------------------------------------------
// SNN two-layer SNU — bit-exact to the np referee (identified rounds 0-9):
//   * matmul: per element, fp32 ascending-k FMA chain, single flush (plain
//     f32 add) at k=512   -> two half-K passes, pass2 does C += chain
//   * recurrence: fp32, numpy op order, NO fma contraction
// Round 14: global_load_lds staging (no VGPR round-trip; r13's reg-prefetch
// spilled at 256 VGPR), row-major LDS [row][32] with chunk-XOR swizzle on
// BOTH sides (linear dest + inverse-swizzled global source + XOR on read).
// Per-element k order unchanged (chunk-major ascending, kk inner) = bit-exact.
// ---------------------------------------------------------------------------

#define TILE 128
#define BK 32              // floats per tile row = 8 chunks of 16B
#define NTILE (512 / BK)   // 16 k-tiles per half pass

typedef const __attribute__((address_space(1))) void* gptr_t;
typedef __attribute__((address_space(3))) void* sptr_t;

template<int ADD>
__global__ __launch_bounds__(256) void gemm_nt_swz(
    const float* __restrict__ A,
    const float* __restrict__ B,
    float* __restrict__ C,
    int N, int M, int K, int kbase)
{
#pragma clang fp contract(off)
    __shared__ float As[TILE * BK];   // [row][32], chunk-swizzled
    __shared__ float Bs[TILE * BK];

    const int tid  = threadIdx.x;
    const int w    = tid >> 6;         // wave 0..3
    const int lane = tid & 63;
    const int tx   = lane & 7;
    const int ty   = lane >> 3;
    const int wr   = w >> 1;
    const int wc   = w & 1;
    const int row0 = wr * 64 + ty * 8;
    const int col0 = wc * 64 + tx * 8;

    const int n0 = blockIdx.x * TILE;
    const int m0 = blockIdx.y * TILE;

    const int lr8 = lane >> 3;         // row within 8-row issue block
    const int lc  = lane & 7;          // LDS chunk slot

    float acc[8][8];
#pragma unroll
    for (int i = 0; i < 8; ++i)
#pragma unroll
        for (int j = 0; j < 8; ++j) acc[i][j] = 0.f;

    for (int kt = 0; kt < NTILE; ++kt) {
        const int k0 = kbase + kt * BK;
        __syncthreads();   // previous compute done reading LDS
#pragma unroll
        for (int is = 0; is < 4; ++is) {
            const int rb   = w * 4 + is;              // 8-row block 0..15
            const int srow = rb * 8 + lr8;            // tile row for this lane
            const int sc   = lc ^ (rb & 7);           // inverse-swizzled source chunk
            const float* ga = A + (size_t)(n0 + srow) * K + k0 + sc * 4;
            const float* gb = B + (size_t)(m0 + srow) * K + k0 + sc * 4;
            __builtin_amdgcn_global_load_lds((gptr_t)ga, (sptr_t)(As + rb * 8 * BK), 16, 0, 0);
            __builtin_amdgcn_global_load_lds((gptr_t)gb, (sptr_t)(Bs + rb * 8 * BK), 16, 0, 0);
        }
        __syncthreads();   // compiler drains vmcnt(0) before barrier

#pragma unroll
        for (int c = 0; c < 8; ++c) {                 // k-chunk, ascending
            float4 bf[8];
#pragma unroll
            for (int j = 0; j < 8; ++j)
                bf[j] = *(const float4*)&Bs[(col0 + j) * BK + ((c ^ tx) << 2)];
#pragma unroll
            for (int i = 0; i < 8; ++i) {
                float4 af = *(const float4*)&As[(row0 + i) * BK + ((c ^ ty) << 2)];
#pragma unroll
                for (int j = 0; j < 8; ++j) {
                    // ascending k within chunk: kk = 0,1,2,3
                    acc[i][j] = __builtin_fmaf(af.x, bf[j].x, acc[i][j]);
                    acc[i][j] = __builtin_fmaf(af.y, bf[j].y, acc[i][j]);
                    acc[i][j] = __builtin_fmaf(af.z, bf[j].z, acc[i][j]);
                    acc[i][j] = __builtin_fmaf(af.w, bf[j].w, acc[i][j]);
                }
            }
        }
    }

#pragma unroll
    for (int i = 0; i < 8; ++i) {
        size_t row = (size_t)(n0 + row0 + i);
        float* Cp = C + row * M + m0 + col0;
        if (ADD) {
            float4 o0 = *(float4*)Cp;
            float4 o1 = *(float4*)(Cp + 4);
            o0.x = o0.x + acc[i][0]; o0.y = o0.y + acc[i][1];
            o0.z = o0.z + acc[i][2]; o0.w = o0.w + acc[i][3];
            o1.x = o1.x + acc[i][4]; o1.y = o1.y + acc[i][5];
            o1.z = o1.z + acc[i][6]; o1.w = o1.w + acc[i][7];
            *(float4*)Cp       = o0;
            *(float4*)(Cp + 4) = o1;
        } else {
            float4 o0 = {acc[i][0], acc[i][1], acc[i][2], acc[i][3]};
            float4 o1 = {acc[i][4], acc[i][5], acc[i][6], acc[i][7]};
            *(float4*)Cp       = o0;
            *(float4*)(Cp + 4) = o1;
        }
    }
}

// Layer-1 recurrence, float4-vectorized, numpy op order, contraction off.
__global__ __launch_bounds__(256) void scan_l1v(
    const float* __restrict__ Z, const float* __restrict__ bias,
    float* __restrict__ spikes, float* __restrict__ mem, int T, int BH)
{
#pragma clang fp contract(off)
    const int BH4 = BH >> 2;
    int i4 = blockIdx.x * blockDim.x + threadIdx.x;
    if (i4 >= BH4) return;
    const float4* Zv = (const float4*)Z;
    float4* spv  = (float4*)spikes;
    float4* memv = (float4*)mem;
    const float4 bb = *(const float4*)&bias[(i4 << 2) & 1023];

    float4 s = {0.f,0.f,0.f,0.f}, y = {0.f,0.f,0.f,0.f};
    float4 z = Zv[i4];
    for (int t = 0; t < T; ++t) {
        size_t idx = (size_t)t * BH4 + i4;
        float4 zn;
        if (t + 1 < T) zn = Zv[idx + BH4]; else zn = make_float4(0.f,0.f,0.f,0.f);
        float u;
        u = z.x + (0.8f * s.x) * (1.0f - y.x); s.x = fmaxf(u, 0.f); y.x = ((s.x + bb.x) > 0.f) ? 1.f : 0.f;
        u = z.y + (0.8f * s.y) * (1.0f - y.y); s.y = fmaxf(u, 0.f); y.y = ((s.y + bb.y) > 0.f) ? 1.f : 0.f;
        u = z.z + (0.8f * s.z) * (1.0f - y.z); s.z = fmaxf(u, 0.f); y.z = ((s.z + bb.z) > 0.f) ? 1.f : 0.f;
        u = z.w + (0.8f * s.w) * (1.0f - y.w); s.w = fmaxf(u, 0.f); y.w = ((s.w + bb.w) > 0.f) ? 1.f : 0.f;
        spv[idx]  = y;
        memv[idx] = s;
        z = zn;
    }
}

// Layer-2 recurrence, float4-vectorized, in place Z2 -> mem2.
__global__ __launch_bounds__(256) void scan_l2v(
    float* __restrict__ Z, const float* __restrict__ bias, int T, int BH)
{
#pragma clang fp contract(off)
    const int BH4 = BH >> 2;
    int i4 = blockIdx.x * blockDim.x + threadIdx.x;
    if (i4 >= BH4) return;
    float4* Zv = (float4*)Z;
    const float4 bb = *(const float4*)&bias[(i4 << 2) & 1023];

    float4 s = {0.f,0.f,0.f,0.f}, y = {0.f,0.f,0.f,0.f};
    float4 z = Zv[i4];
    for (int t = 0; t < T; ++t) {
        size_t idx = (size_t)t * BH4 + i4;
        float4 zn;
        if (t + 1 < T) zn = Zv[idx + BH4]; else zn = make_float4(0.f,0.f,0.f,0.f);
        float u;
        u = z.x + (0.8f * s.x) * (1.0f - y.x); s.x = fmaxf(u, 0.f); y.x = ((s.x + bb.x) > 0.f) ? 1.f : 0.f;
        u = z.y + (0.8f * s.y) * (1.0f - y.y); s.y = fmaxf(u, 0.f); y.y = ((s.y + bb.y) > 0.f) ? 1.f : 0.f;
        u = z.z + (0.8f * s.z) * (1.0f - y.z); s.z = fmaxf(u, 0.f); y.z = ((s.z + bb.z) > 0.f) ? 1.f : 0.f;
        u = z.w + (0.8f * s.w) * (1.0f - y.w); s.w = fmaxf(u, 0.f); y.w = ((s.w + bb.w) > 0.f) ? 1.f : 0.f;
        Zv[idx] = s;
        z = zn;
    }
}

extern "C" void kernel_launch(void* const* d_in, const int* in_sizes, int n_in,
                              void* d_out, int out_size, void* d_ws, size_t ws_size,
                              hipStream_t stream)
{
    (void)in_sizes; (void)n_in; (void)out_size; (void)d_ws; (void)ws_size;

    const float* x  = (const float*)d_in[0];   // [T,B,IN]
    const float* W1 = (const float*)d_in[1];   // [H,IN]
    const float* b1 = (const float*)d_in[2];   // [H]
    const float* W2 = (const float*)d_in[3];   // [H,H]
    const float* b2 = (const float*)d_in[4];   // [H]
    float* out = (float*)d_out;

    const int T = 100, Bsz = 256, IN = 1024, H = 1024;
    const int N  = T * Bsz;                 // 25600
    const int BH = Bsz * H;                 // 262144
    const size_t TBH = (size_t)T * BH;      // 26214400

    float* spikes = out;                    // output 0
    float* mem1   = out + TBH;              // output 1
    float* zbuf   = out + 2 * TBH;          // Z1 -> Z2 -> mem2 (in place)

    dim3 ggrid(N / TILE, H / TILE);         // 200 x 8
    dim3 gblk(256);
    dim3 sgrid((BH / 4) / 256);             // 256 blocks
    dim3 sblk(256);

    // Z1 = X @ W1^T  (two k-half passes, bit-exact KC=512 join)
    gemm_nt_swz<0><<<ggrid, gblk, 0, stream>>>(x, W1, zbuf, N, H, IN, 0);
    gemm_nt_swz<1><<<ggrid, gblk, 0, stream>>>(x, W1, zbuf, N, H, IN, 512);
    // layer-1 scan -> spikes, mem1
    scan_l1v<<<sgrid, sblk, 0, stream>>>(zbuf, b1, spikes, mem1, T, BH);
    // Z2 = spikes @ W2^T
    gemm_nt_swz<0><<<ggrid, gblk, 0, stream>>>(spikes, W2, zbuf, N, H, H, 0);
    gemm_nt_swz<1><<<ggrid, gblk, 0, stream>>>(spikes, W2, zbuf, N, H, H, 512);
    // layer-2 scan in place -> mem2
    scan_l2v<<<sgrid, sblk, 0, stream>>>(zbuf, b2, T, BH);
}